// Round 13
// baseline (311.084 us; speedup 1.0000x reference)
//
#include <hip/hip_runtime.h>
#include <hip/hip_fp16.h>

#define N_NODES 50000
#define N_EDGES 600000
#define N_GRAPHS 64
#define HID 128
#define OUT_C 32

#define N_SCAN_BLOCKS ((N_NODES + 255) / 256)   // 196
#define SCAN_FLAG 0x40000000

typedef __attribute__((ext_vector_type(8))) _Float16 half8;
typedef __attribute__((ext_vector_type(4))) float f32x4;

// ================= prep: zero counters + fp16 casts + graph boundaries =================
// zero region (contiguous ints): degi[50000] bsum[196]   (cursor now init'd by scan)
#define ZERO_INTS (N_NODES + N_SCAN_BLOCKS)

__global__ __launch_bounds__(256) void prep_kernel(
    const float* __restrict__ x, const int* __restrict__ batch,
    const float* __restrict__ W1l, const float* __restrict__ W1r,
    const float* __restrict__ W2l, const float* __restrict__ W2r,
    __half* __restrict__ xh, __half* __restrict__ Wt1, __half* __restrict__ Wt2,
    int* __restrict__ zero_base, int* __restrict__ gstart) {
    const int b = blockIdx.x;
    const int t = threadIdx.x;
    const int gtid = b * 256 + t;
    const int gsz = gridDim.x * 256;
    for (int i = gtid; i < ZERO_INTS; i += gsz) zero_base[i] = 0;

    // graph boundaries from sorted batch
    for (int i = gtid; i <= N_NODES; i += gsz) {
        if (i == 0) {
            int b1 = batch[0];
            for (int g = 0; g <= b1; ++g) gstart[g] = 0;
        } else if (i == N_NODES) {
            int b0 = batch[N_NODES - 1];
            for (int g = b0 + 1; g <= N_GRAPHS; ++g) gstart[g] = N_NODES;
        } else {
            int b0 = batch[i - 1], b1 = batch[i];
            for (int g = b0 + 1; g <= b1; ++g) gstart[g] = i;
        }
    }

    if (b < 16) {
        for (int i = gtid; i < 65536; i += 4096) {
            int which = i >> 15;
            int j = i & 32767;
            int n = j >> 8, k = j & 255;
            const float* Wl = which ? W2l : W1l;
            const float* Wr = which ? W2r : W1r;
            float a = (k < 128) ? Wl[n * 128 + k] : Wr[n * 128 + (k - 128)];
            (which ? Wt2 : Wt1)[j] = __float2half(a);
        }
    } else {
        int i = ((b - 16) * 256 + t) * 4;
        if (i < N_NODES * 128) {
            float4 v = *(const float4*)(x + i);
            __half2 a = __floats2half2_rn(v.x, v.y);
            __half2 c = __floats2half2_rn(v.z, v.w);
            uint2 st;
            st.x = *(const unsigned int*)&a;
            st.y = *(const unsigned int*)&c;
            *(uint2*)(xh + i) = st;
        }
    }
}

// ================= CSR: degrees =================
__global__ void deg_kernel(const int* __restrict__ dst, int* __restrict__ deg, int E) {
    int e = blockIdx.x * 256 + threadIdx.x;
    if (e < E) atomicAdd(&deg[dst[e]], 1);
}

// ================= CSR: single-dispatch scan (decoupled lookback) =================
// also initializes cursor = rowptr so fill needs only one atomic per edge
__global__ __launch_bounds__(256) void scan_fused(
    const int* __restrict__ deg, int* __restrict__ bsum,
    int* __restrict__ rowptr, int* __restrict__ cursor, float* __restrict__ invdeg) {
    __shared__ int s[256];
    const int b = blockIdx.x;
    const int t = threadIdx.x;
    const int idx = b * 256 + t;
    const int v = (idx < N_NODES) ? deg[idx] : 0;
    s[t] = v;
    __syncthreads();
    for (int off = 1; off < 256; off <<= 1) {
        int u = (t >= off) ? s[t - off] : 0;
        __syncthreads();
        s[t] += u;
        __syncthreads();
    }
    const int incl = s[t];
    if (t == 255) atomicExch(&bsum[b], incl | SCAN_FLAG);

    int pv = 0;
    if (t < b) {
        int w;
        do { w = atomicAdd(&bsum[t], 0); } while (!(w & SCAN_FLAG));
        pv = w & ~SCAN_FLAG;
    }
    __syncthreads();
    s[t] = pv;
    __syncthreads();
    for (int off = 128; off > 0; off >>= 1) {
        if (t < off) s[t] += s[t + off];
        __syncthreads();
    }
    const int boffs = s[0];

    if (idx < N_NODES) {
        int rp = boffs + incl - v;
        rowptr[idx] = rp;
        cursor[idx] = rp;
        invdeg[idx] = 1.0f / fmaxf((float)v, 1.0f);
    }
    if (b == N_SCAN_BLOCKS - 1 && t == 255) rowptr[N_NODES] = boffs + incl;
}

// ================= CSR: fill (single atomic, absolute position) =================
__global__ void fill_kernel(const int* __restrict__ src, const int* __restrict__ dst,
                            int* __restrict__ cursor, int* __restrict__ eidx, int E) {
    int e = blockIdx.x * 256 + threadIdx.x;
    if (e < E) {
        int pos = atomicAdd(&cursor[dst[e]], 1);
        eidx[pos] = src[e];
    }
}

// ================= fused SAGE layer: gather-aggregate into LDS + MFMA GEMM =================
// Block = 64 rows. Phase 1: 4 waves x (4 passes x 4 nodes x 16 lanes x 16B) gather mean
// into As (fp16). Phase 2: MFMA, A from LDS (k<128) / prefetched regs (k>=128),
// B direct from global Wt (L2-broadcast across blocks).
#define GBM 64
#define ALD 136   // halfs per As row: 128 + 8 pad (16B)

#define AGG8(vv, aa, ab) { aa.x += (float)vv[0]; aa.y += (float)vv[1]; \
                           aa.z += (float)vv[2]; aa.w += (float)vv[3]; \
                           ab.x += (float)vv[4]; ab.y += (float)vv[5]; \
                           ab.z += (float)vv[6]; ab.w += (float)vv[7]; }

__global__ __launch_bounds__(256) void sage_layer_f16(
    const __half* __restrict__ feat16, const int* __restrict__ rowptr,
    const int* __restrict__ eidx, const float* __restrict__ invdeg,
    const __half* __restrict__ Wt, const float* __restrict__ bias,
    __half* __restrict__ out16, int M) {
    __shared__ __align__(16) __half As[GBM][ALD];

    const int tid = threadIdx.x;
    const int wave = tid >> 6;
    const int lane = tid & 63;
    const int l15 = lane & 15;
    const int quad = lane >> 4;      // also nh (node-in-pass) for gather
    const int row0 = blockIdx.x * GBM;
    const size_t coff = (size_t)l15 * 8;

    // prefetch feat-half A fragments (k>=128) early; clamp OOB rows (stores guarded)
    const int gi_a = min(row0 + wave * 16 + l15, M - 1);
    half8 af_hi[4];
#pragma unroll
    for (int kb = 0; kb < 4; ++kb)
        af_hi[kb] = *(const half8*)(feat16 + (size_t)gi_a * 128 + kb * 32 + quad * 8);

    // ---- phase 1: gather means for this block's 64 rows
    for (int p = 0; p < 4; ++p) {
        const int lrow = wave * 16 + p * 4 + quad;
        const int node = row0 + lrow;
        const bool act = (node < M);
        int beg = 0, end = 0;
        if (act) { beg = rowptr[node]; end = rowptr[node + 1]; }

        float4 a0 = {0.f,0.f,0.f,0.f}, b0 = {0.f,0.f,0.f,0.f};
        float4 a1 = {0.f,0.f,0.f,0.f}, b1 = {0.f,0.f,0.f,0.f};
        float4 a2 = {0.f,0.f,0.f,0.f}, b2 = {0.f,0.f,0.f,0.f};
        float4 a3 = {0.f,0.f,0.f,0.f}, b3 = {0.f,0.f,0.f,0.f};
        int i = beg;
        for (; i + 8 <= end; i += 8) {
            int s0 = eidx[i+0], s1 = eidx[i+1], s2 = eidx[i+2], s3 = eidx[i+3];
            int s4 = eidx[i+4], s5 = eidx[i+5], s6 = eidx[i+6], s7 = eidx[i+7];
            half8 v0 = *(const half8*)(feat16 + (size_t)s0 * 128 + coff);
            half8 v1 = *(const half8*)(feat16 + (size_t)s1 * 128 + coff);
            half8 v2 = *(const half8*)(feat16 + (size_t)s2 * 128 + coff);
            half8 v3 = *(const half8*)(feat16 + (size_t)s3 * 128 + coff);
            half8 v4 = *(const half8*)(feat16 + (size_t)s4 * 128 + coff);
            half8 v5 = *(const half8*)(feat16 + (size_t)s5 * 128 + coff);
            half8 v6 = *(const half8*)(feat16 + (size_t)s6 * 128 + coff);
            half8 v7 = *(const half8*)(feat16 + (size_t)s7 * 128 + coff);
            AGG8(v0, a0, b0); AGG8(v1, a1, b1); AGG8(v2, a2, b2); AGG8(v3, a3, b3);
            AGG8(v4, a0, b0); AGG8(v5, a1, b1); AGG8(v6, a2, b2); AGG8(v7, a3, b3);
        }
        if (i + 4 <= end) {
            int s0 = eidx[i+0], s1 = eidx[i+1], s2 = eidx[i+2], s3 = eidx[i+3];
            half8 v0 = *(const half8*)(feat16 + (size_t)s0 * 128 + coff);
            half8 v1 = *(const half8*)(feat16 + (size_t)s1 * 128 + coff);
            half8 v2 = *(const half8*)(feat16 + (size_t)s2 * 128 + coff);
            half8 v3 = *(const half8*)(feat16 + (size_t)s3 * 128 + coff);
            AGG8(v0, a0, b0); AGG8(v1, a1, b1); AGG8(v2, a2, b2); AGG8(v3, a3, b3);
            i += 4;
        }
        if (i + 2 <= end) {
            int s0 = eidx[i+0], s1 = eidx[i+1];
            half8 v0 = *(const half8*)(feat16 + (size_t)s0 * 128 + coff);
            half8 v1 = *(const half8*)(feat16 + (size_t)s1 * 128 + coff);
            AGG8(v0, a0, b0); AGG8(v1, a1, b1);
            i += 2;
        }
        if (i < end) {
            int s0 = eidx[i];
            half8 v0 = *(const half8*)(feat16 + (size_t)s0 * 128 + coff);
            AGG8(v0, a0, b0);
        }

        const float sc = act ? invdeg[node] : 0.0f;
        half8 r;
        r[0] = (_Float16)(((a0.x + a1.x) + (a2.x + a3.x)) * sc);
        r[1] = (_Float16)(((a0.y + a1.y) + (a2.y + a3.y)) * sc);
        r[2] = (_Float16)(((a0.z + a1.z) + (a2.z + a3.z)) * sc);
        r[3] = (_Float16)(((a0.w + a1.w) + (a2.w + a3.w)) * sc);
        r[4] = (_Float16)(((b0.x + b1.x) + (b2.x + b3.x)) * sc);
        r[5] = (_Float16)(((b0.y + b1.y) + (b2.y + b3.y)) * sc);
        r[6] = (_Float16)(((b0.z + b1.z) + (b2.z + b3.z)) * sc);
        r[7] = (_Float16)(((b0.w + b1.w) + (b2.w + b3.w)) * sc);
        *(half8*)&As[lrow][l15 * 8] = r;
    }

    __syncthreads();

    // ---- phase 2: GEMM
    f32x4 acc[8];
#pragma unroll
    for (int t = 0; t < 8; ++t) acc[t] = (f32x4){0.f, 0.f, 0.f, 0.f};

#pragma unroll
    for (int kb = 0; kb < 8; ++kb) {
        const half8 a = (kb < 4) ? *(const half8*)&As[wave * 16 + l15][kb * 32 + quad * 8]
                                 : af_hi[kb - 4];
#pragma unroll
        for (int t = 0; t < 8; ++t) {
            const half8 b = *(const half8*)(Wt + (size_t)(t * 16 + l15) * 256 + kb * 32 + quad * 8);
            acc[t] = __builtin_amdgcn_mfma_f32_16x16x32_f16(a, b, acc[t], 0, 0, 0);
        }
    }

    // epilogue: row = row0 + wave*16 + quad*4 + r, col = t*16 + l15
#pragma unroll
    for (int r = 0; r < 4; ++r) {
        int gi = row0 + wave * 16 + quad * 4 + r;
        if (gi < M) {
#pragma unroll
            for (int t = 0; t < 8; ++t) {
                int col = t * 16 + l15;
                float v = fmaxf(acc[t][r] + bias[col], 0.f);
                out16[(size_t)gi * 128 + col] = __float2half(v);
            }
        }
    }
}

// ================= pooling: per-part partial sums, boundaries from gstart =================
#define POOL_PARTS 4
__global__ __launch_bounds__(256) void pool_parts(
    const __half* __restrict__ h, const int* __restrict__ gstart,
    float* __restrict__ pooled_parts) {
    const int g = blockIdx.x >> 2;
    const int part = blockIdx.x & 3;
    const int start = gstart[g];
    const int end = gstart[g + 1];

    const int t = threadIdx.x;
    const int c4 = (t & 31) * 4;
    const int rg = t >> 5;
    float4 acc = {0.f, 0.f, 0.f, 0.f};
    for (int n = start + part * 8 + rg; n < end; n += 8 * POOL_PARTS) {
        const __half2* p = (const __half2*)(h + (size_t)n * 128 + c4);
        float2 f0 = __half22float2(p[0]);
        float2 f1 = __half22float2(p[1]);
        acc.x += f0.x; acc.y += f0.y; acc.z += f1.x; acc.w += f1.y;
    }
    __shared__ float sm[8][132];
    sm[rg][c4 + 0] = acc.x;
    sm[rg][c4 + 1] = acc.y;
    sm[rg][c4 + 2] = acc.z;
    sm[rg][c4 + 3] = acc.w;
    __syncthreads();
    if (t < 128) {
        float s = 0.f;
#pragma unroll
        for (int r = 0; r < 8; ++r) s += sm[r][t];
        pooled_parts[(size_t)blockIdx.x * 128 + t] = s;
    }
}

// ================= final linear =================
__global__ void final_kernel(const float* __restrict__ pooled_parts,
                             const int* __restrict__ gstart,
                             const float* __restrict__ Wlin, const float* __restrict__ blin,
                             float* __restrict__ out) {
    int g = blockIdx.x;
    int j = threadIdx.x;               // 0..31
    float inv = 1.0f / fmaxf((float)(gstart[g + 1] - gstart[g]), 1.0f);
    float sum = blin[j];
    const float* w = Wlin + j * 128;
    const float* p0 = pooled_parts + (size_t)(g * 4 + 0) * 128;
    const float* p1 = pooled_parts + (size_t)(g * 4 + 1) * 128;
    const float* p2 = pooled_parts + (size_t)(g * 4 + 2) * 128;
    const float* p3 = pooled_parts + (size_t)(g * 4 + 3) * 128;
    for (int c = 0; c < 128; ++c) {
        float p = (p0[c] + p1[c]) + (p2[c] + p3[c]);
        sum += p * inv * w[c];
    }
    out[g * 32 + j] = sum;
}

extern "C" void kernel_launch(void* const* d_in, const int* in_sizes, int n_in,
                              void* d_out, int out_size, void* d_ws, size_t ws_size,
                              hipStream_t stream) {
    const float* x    = (const float*)d_in[0];
    const int*   src  = (const int*)d_in[1];
    const int*   dst  = ((const int*)d_in[1]) + N_EDGES;
    const int*   batch= (const int*)d_in[2];
    const float* W1l  = (const float*)d_in[3];
    const float* b1   = (const float*)d_in[4];
    const float* W1r  = (const float*)d_in[5];
    const float* W2l  = (const float*)d_in[6];
    const float* b2   = (const float*)d_in[7];
    const float* W2r  = (const float*)d_in[8];
    const float* Wlin = (const float*)d_in[9];
    const float* blin = (const float*)d_in[10];
    float* out = (float*)d_out;

    __half* xh     = (__half*)d_ws;                 // 6,400,000 h
    __half* h1_16  = xh + 6400000;                  // 6,400,000 h
    __half* h2_16  = h1_16 + 6400000;               // 6,400,000 h
    __half* Wt1    = h2_16 + 6400000;               // 32,768 h
    __half* Wt2    = Wt1 + 32768;                   // 32,768 h
    float* pooled_parts = (float*)(Wt2 + 32768);    // 32,768 f
    float* invdeg  = pooled_parts + 32768;          // 50,000 f
    int*   gstart  = (int*)(invdeg + N_NODES);      // 65 i
    // contiguous zero region: degi, bsum
    int*   degi    = gstart + 65;                   // 50,000 i
    int*   bsum    = degi + N_NODES;                // 196 i
    int*   cursor  = bsum + N_SCAN_BLOCKS;          // 50,000 i (init'd by scan)
    int*   rowptr  = cursor + N_NODES;              // 50,001 i
    int*   eidx    = rowptr + N_NODES + 1;          // 600,000 i

    // 1) prep: zero counters + casts + graph boundaries
    prep_kernel<<<16 + (N_NODES * 128 / 4 + 255) / 256, 256, 0, stream>>>(
        x, batch, W1l, W1r, W2l, W2r, xh, Wt1, Wt2, degi, gstart);

    // 2-4) CSR: degrees -> fused lookback scan (also inits cursor) -> fill
    deg_kernel<<<(N_EDGES + 255) / 256, 256, 0, stream>>>(dst, degi, N_EDGES);
    scan_fused<<<N_SCAN_BLOCKS, 256, 0, stream>>>(degi, bsum, rowptr, cursor, invdeg);
    fill_kernel<<<(N_EDGES + 255) / 256, 256, 0, stream>>>(src, dst, cursor, eidx, N_EDGES);

    const int layer_grid = (N_NODES + GBM - 1) / GBM;   // 782

    // 5) layer 1 fused (gather + GEMM), 6) layer 2 fused
    sage_layer_f16<<<layer_grid, 256, 0, stream>>>(xh, rowptr, eidx, invdeg, Wt1, b1, h1_16, N_NODES);
    sage_layer_f16<<<layer_grid, 256, 0, stream>>>(h1_16, rowptr, eidx, invdeg, Wt2, b2, h2_16, N_NODES);

    // 7-8) pool partials + final linear
    pool_parts<<<N_GRAPHS * POOL_PARTS, 256, 0, stream>>>(h2_16, gstart, pooled_parts);
    final_kernel<<<N_GRAPHS, 32, 0, stream>>>(pooled_parts, gstart, Wlin, blin, out);
}